// Round 6
// baseline (443.892 us; speedup 1.0000x reference)
//
#include <hip/hip_runtime.h>
#include <hip/hip_bf16.h>
#include <math.h>

typedef __attribute__((ext_vector_type(8))) short bf16x8;
typedef __attribute__((ext_vector_type(4))) float f32x4;

#define FRAME_PAD (66*66*128)   // padded NHWC frame elems (557568)

#define GLOAD_LDS16(g, l) \
    __builtin_amdgcn_global_load_lds((const __attribute__((address_space(1))) void*)(g), \
                                     (__attribute__((address_space(3))) void*)(l), 16, 0, 0)

#define WAITV4    asm volatile("s_waitcnt vmcnt(4)" ::: "memory")
#define WAITV0    asm volatile("s_waitcnt vmcnt(0)" ::: "memory")
#define SBAR      __builtin_amdgcn_s_barrier()
#define MEMPIN    asm volatile("" ::: "memory")

__device__ __forceinline__ float sigmoidf_(float x) { return 1.0f / (1.0f + __expf(-x)); }
__device__ __forceinline__ float tanhf_(float x) {
    x = fminf(fmaxf(x, -15.0f), 15.0f);
    float e = __expf(2.0f * x);
    return (e - 1.0f) / (e + 1.0f);
}
__device__ __forceinline__ float b2f_(short u) {
    unsigned int v = ((unsigned int)(unsigned short)u) << 16;
    return __builtin_bit_cast(float, v);
}
__device__ __forceinline__ short f2b_(float f) {
    __hip_bfloat16 hb = __float2bfloat16(f);
    return *reinterpret_cast<short*>(&hb);
}

// ---------- weights: W[oc][ic][tap] f32 -> Wt[tap][n'][ic] bf16, n' = c*4 + gate ----------
__global__ void wt_kernel(const float* __restrict__ w, __hip_bfloat16* __restrict__ wt)
{
    int idx = blockIdx.x * 256 + threadIdx.x;       // tap*131072 + n*256 + ic
    if (idx >= 9 * 512 * 256) return;
    int ic  = idx & 255;
    int n   = (idx >> 8) & 511;
    int tap = idx >> 17;
    int c = n >> 2, g = n & 3;                       // gate 0:i 1:f 2:o 3:g
    int oc = g * 128 + c;
    wt[idx] = __float2bfloat16(w[((size_t)oc * 256 + (size_t)ic) * 9 + tap]);
}

// ---------- zero the pad borders of all x and h frames ----------
__global__ void border_kernel(__hip_bfloat16* __restrict__ x_pad,
                              __hip_bfloat16* __restrict__ h_pad)
{
    const int fr = blockIdx.x;                        // 0..31 x, 32..63 h
    __hip_bfloat16* base = (fr < 32) ? x_pad + (size_t)fr * FRAME_PAD
                                     : h_pad + (size_t)(fr - 32) * FRAME_PAD;
    bf16x8 z = {};
    for (int u = threadIdx.x; u < 2112; u += 256) {
        int half = (u >= 1056) ? 1 : 0;
        int v = u - half * 1056;
        *(bf16x8*)(base + (size_t)(half * 65 * 66) * 128 + (size_t)v * 8) = z;
    }
    for (int u = threadIdx.x; u < 2048; u += 256) {
        int yy = 1 + (u >> 5);
        int r = u & 31;
        int side = r >> 4, c16 = r & 15;
        *(bf16x8*)(base + (size_t)(yy * 66 + side * 65) * 128 + (size_t)c16 * 8) = z;
    }
}

// ---------- x: NCHW f32 -> padded NHWC bf16 (vectorized, LDS stride-129 transpose) ----------
__global__ void xpose_kernel(const float* __restrict__ x, __hip_bfloat16* __restrict__ x_pad)
{
    __shared__ float tile[64][129];                  // [x][c]
    const int f = blockIdx.x >> 6;
    const int y = blockIdx.x & 63;
    const int tid = threadIdx.x;
    const float* src = x + (size_t)f * 524288 + (size_t)y * 64;
    #pragma unroll
    for (int it = 0; it < 8; ++it) {
        int c  = it * 16 + (tid >> 4);
        int xq = tid & 15;
        float4 v = *(const float4*)(src + (size_t)c * 4096 + xq * 4);
        tile[xq * 4 + 0][c] = v.x;
        tile[xq * 4 + 1][c] = v.y;
        tile[xq * 4 + 2][c] = v.z;
        tile[xq * 4 + 3][c] = v.w;
    }
    __syncthreads();
    __hip_bfloat16* dst = x_pad + (size_t)f * FRAME_PAD + (size_t)((y + 1) * 66 + 1) * 128;
    const int g = tid & 15;
    #pragma unroll
    for (int it = 0; it < 4; ++it) {
        int xr = it * 16 + (tid >> 4);
        bf16x8 o;
        #pragma unroll
        for (int e = 0; e < 8; ++e) o[e] = f2b_(tile[xr][g * 8 + e]);
        *(bf16x8*)(dst + (size_t)xr * 128 + g * 8) = o;
    }
}

// ---------- fused conv-GEMM + LSTM gates; 128x128 tile, ring-3, 2 blocks/CU ----------
// D[n'][m]: n' = c*4+gate (512, BN=128), m = spatial (16384, BM=128).
// K tiles of BK=32: T0 -> 36 (x only), else 72. Ring-3: stage(kt+2) targets the slot
// whose readers all finished at kt-1 (their ds_reads were consumed by kt-1 MFMAs
// before the top-of-kt barrier) -> no lgkm drain needed. 48KB LDS/block -> 2 blocks
// co-resident per CU: one block's MFMA covers the other's WAITV+SBAR drain (m114).
template<bool T0>
__global__ __launch_bounds__(256, 2)
void conv_gemm(const __hip_bfloat16* __restrict__ x_pad,
               const __hip_bfloat16* __restrict__ h_pad,
               const __hip_bfloat16* __restrict__ wt,
               const float* __restrict__ bias,
               float* __restrict__ c_state, int t)
{
    __shared__ alignas(16) __hip_bfloat16 S_s[3][128 * 32];   // spatial ring, 3x8KB
    __shared__ alignas(16) __hip_bfloat16 W_s[3][128 * 32];   // weight ring,  3x8KB
    const int tid  = threadIdx.x;
    const int wv   = tid >> 6;
    const int lane = tid & 63;
    const int KT   = T0 ? 36 : 72;

    // XCD-chunked remap: each XCD owns 64 consecutive tiles (16 m-panels x 4 n-blocks).
    const int F    = blockIdx.x;                 // 512 blocks
    const int tile = (F >> 3) + (F & 7) * 64;
    const int n0   = (tile & 3) * 128;
    const int mblk = tile >> 2;                  // 0..127
    const int b    = mblk >> 5;
    const int y0   = (mblk & 31) * 2;
    const int m0   = mblk * 128;

    const __hip_bfloat16* xf = x_pad + (size_t)(b * 8 + t) * FRAME_PAD;
    const __hip_bfloat16* hf = h_pad + (size_t)(b * 8 + (T0 ? 0 : t - 1)) * FRAME_PAD;

    // staging offsets; source pre-swizzled q_src = q ^ ((row>>1)&3) (2-way alias = free)
    int aOff[2], bOff[2];
    #pragma unroll
    for (int j = 0; j < 2; ++j) {
        int sid = j * 256 + tid;
        int row = sid >> 2;
        int q   = (sid & 3) ^ ((row >> 1) & 3);
        aOff[j] = ((y0 + (row >> 6)) * 66 + (row & 63)) * 128 + q * 8;
        bOff[j] = (n0 + row) * 256 + q * 8;
    }

    auto STAGE = [&](__hip_bfloat16* Sl, __hip_bfloat16* Wl, int kt) {
        int tap, icq;
        const __hip_bfloat16* sb;
        if constexpr (T0) { tap = kt >> 2; icq = (kt & 3) * 32; sb = xf + icq; }
        else { tap = kt >> 3; icq = (kt & 7) * 32;
               sb = (icq < 128) ? (xf + icq) : (hf + (icq - 128)); }
        const int dy = tap / 3, dx = tap % 3;
        const __hip_bfloat16* a = sb + (dy * 66 + dx) * 128;
        #pragma unroll
        for (int j = 0; j < 2; ++j)
            GLOAD_LDS16(a + aOff[j], Sl + (size_t)(j * 256 + tid) * 8);
        const __hip_bfloat16* bsrc = wt + tap * 131072 + icq;
        #pragma unroll
        for (int j = 0; j < 2; ++j)
            GLOAD_LDS16(bsrc + bOff[j], Wl + (size_t)(j * 256 + tid) * 8);
    };

    // fragment read offsets; slot = fq ^ ((fr>>1)&3) is lane-constant (rows are
    // base+fr with base % 16 == 0), giving exactly 2-way bank aliasing (free).
    const int wm = wv >> 1, wn = wv & 1;
    const int fr = lane & 15, fq = lane >> 4;
    const int slot = (fq ^ ((fr >> 1) & 3)) * 8;
    const int sA0 = (wm * 64 + fr) * 32 + slot;
    const int wB0 = (wn * 64 + fr) * 32 + slot;

    f32x4 acc[4][4] = {};

    __hip_bfloat16 *Sr = &S_s[0][0], *Sn = &S_s[1][0], *Sf = &S_s[2][0];
    __hip_bfloat16 *Wr = &W_s[0][0], *Wn = &W_s[1][0], *Wf = &W_s[2][0];

    STAGE(Sr, Wr, 0);
    STAGE(Sn, Wn, 1);                            // 8 loads/thread in flight

    #pragma unroll 1
    for (int kt = 0; kt < KT; ++kt) {
        if (kt < KT - 1) { WAITV4; } else { WAITV0; }   // tile kt landed (own share)
        SBAR;                                           // everyone's share landed
        MEMPIN;                                         // pin ds_reads below barrier
        if (kt < KT - 2) STAGE(Sf, Wf, kt + 2);         // slot retired at kt-1

        bf16x8 w[4], s[4];
        #pragma unroll
        for (int ri = 0; ri < 4; ++ri) w[ri] = *(const bf16x8*)(Wr + wB0 + ri * 512);
        #pragma unroll
        for (int ci = 0; ci < 4; ++ci) s[ci] = *(const bf16x8*)(Sr + sA0 + ci * 512);
        __builtin_amdgcn_s_setprio(1);
        #pragma unroll
        for (int ri = 0; ri < 4; ++ri)
            #pragma unroll
            for (int ci = 0; ci < 4; ++ci)
                acc[ri][ci] = __builtin_amdgcn_mfma_f32_16x16x32_bf16(w[ri], s[ci], acc[ri][ci], 0, 0, 0);
        __builtin_amdgcn_s_setprio(0);

        __hip_bfloat16* tp = Sr; Sr = Sn; Sn = Sf; Sf = tp;
        __hip_bfloat16* tw = Wr; Wr = Wn; Wn = Wf; Wf = tw;
    }

    // ---------- fused LSTM gate epilogue (identical math to validated rounds) ----------
    const int c0    = (n0 >> 2) + wn * 16;
    const int mcol0 = m0 + wm * 64 + fr;
    __hip_bfloat16* hout = (__hip_bfloat16*)h_pad + (size_t)(b * 8 + t) * FRAME_PAD;
    #pragma unroll
    for (int ri = 0; ri < 4; ++ri) {
        const int c = c0 + ri * 4 + fq;
        const float bi  = bias[c];
        const float bfv = bias[128 + c];
        const float bo  = bias[256 + c];
        const float bg  = bias[384 + c];
        float* csrow = c_state + (size_t)c * 16384;
        #pragma unroll
        for (int ci = 0; ci < 4; ++ci) {
            const int m = mcol0 + ci * 16;
            const int s = m & 4095;
            const float cold = T0 ? 0.0f : csrow[m];
            const float zi = acc[ri][ci][0] + bi;
            const float zf = acc[ri][ci][1] + bfv;
            const float zo = acc[ri][ci][2] + bo;
            const float zg = acc[ri][ci][3] + bg;
            const float cn = sigmoidf_(zf) * cold + sigmoidf_(zi) * tanhf_(zg);
            const float h  = sigmoidf_(zo) * tanhf_(cn);
            csrow[m] = cn;
            hout[(size_t)(((s >> 6) + 1) * 66 + (s & 63) + 1) * 128 + c] = __float2bfloat16(h);
        }
    }
}

// ---------- final: padded-NHWC bf16 h -> NCHW f32 out, BN(eval)+ReLU fused in load ----------
__global__ void bn_out_kernel(const __hip_bfloat16* __restrict__ h_pad,
                              const float* __restrict__ gamma, const float* __restrict__ beta,
                              const float* __restrict__ rmean, const float* __restrict__ rvar,
                              float* __restrict__ out)
{
    __shared__ float tile[64][129];                  // [x][c], post-BN values
    __shared__ float sc_s[128], sh_s[128];
    const int fo  = blockIdx.x >> 6;                 // frame = b*8+t = h slot
    const int y   = blockIdx.x & 63;
    const int tid = threadIdx.x;
    if (tid < 128) {
        float sc = gamma[tid] * rsqrtf(rvar[tid] + 1e-5f);
        sc_s[tid] = sc;
        sh_s[tid] = beta[tid] - rmean[tid] * sc;
    }
    __syncthreads();
    const __hip_bfloat16* src =
        h_pad + (size_t)fo * FRAME_PAD + (size_t)((y + 1) * 66 + 1) * 128;
    const int g = tid & 15;
    float sc[8], sh[8];
    #pragma unroll
    for (int e = 0; e < 8; ++e) { sc[e] = sc_s[g * 8 + e]; sh[e] = sh_s[g * 8 + e]; }
    #pragma unroll
    for (int it = 0; it < 4; ++it) {
        int xr = it * 16 + (tid >> 4);
        bf16x8 v = *(const bf16x8*)(src + (size_t)xr * 128 + g * 8);
        #pragma unroll
        for (int e = 0; e < 8; ++e)
            tile[xr][g * 8 + e] = fmaxf(b2f_(v[e]) * sc[e] + sh[e], 0.0f);
    }
    __syncthreads();
    float* dst = out + (size_t)fo * 524288 + (size_t)y * 64;
    #pragma unroll
    for (int it = 0; it < 8; ++it) {
        int c  = it * 16 + (tid >> 4);
        int xq = tid & 15;
        float4 o;
        o.x = tile[xq * 4 + 0][c];
        o.y = tile[xq * 4 + 1][c];
        o.z = tile[xq * 4 + 2][c];
        o.w = tile[xq * 4 + 3][c];
        *(float4*)(dst + (size_t)c * 4096 + xq * 4) = o;
    }
}

extern "C" void kernel_launch(void* const* d_in, const int* in_sizes, int n_in,
                              void* d_out, int out_size, void* d_ws, size_t ws_size,
                              hipStream_t stream)
{
    const float* x      = (const float*)d_in[0];
    const float* w_conv = (const float*)d_in[1];
    const float* b_conv = (const float*)d_in[2];
    const float* gamma  = (const float*)d_in[3];
    const float* beta   = (const float*)d_in[4];
    const float* rmean  = (const float*)d_in[5];
    const float* rvar   = (const float*)d_in[6];
    float* out = (float*)d_out;

    // workspace layout (bytes)
    //   Wt      @ 0          : 9*512*256*2    = 2,359,296
    //   x_pad   @ 2359296    : 32*66*66*128*2 = 35,684,352
    //   h_pad   @ 38043648   : 32*66*66*128*2 = 35,684,352   (slot b*8+t = h after step t)
    //   c_state @ 73728000   : 128*16384*4    = 8,388,608    ([c][m]; written before read)
    //   total 82,116,608
    if (ws_size < 82116608u) return;

    char* ws = (char*)d_ws;
    __hip_bfloat16* Wt    = (__hip_bfloat16*)(ws);
    __hip_bfloat16* x_pad = (__hip_bfloat16*)(ws + 2359296);
    __hip_bfloat16* h_pad = (__hip_bfloat16*)(ws + 38043648);
    float* c_state        = (float*)(ws + 73728000);

    wt_kernel<<<4608, 256, 0, stream>>>(w_conv, Wt);
    xpose_kernel<<<2048, 256, 0, stream>>>(x, x_pad);
    border_kernel<<<64, 256, 0, stream>>>(x_pad, h_pad);

    conv_gemm<true><<<512, 256, 0, stream>>>(x_pad, h_pad, Wt, b_conv, c_state, 0);
    for (int t = 1; t < 8; ++t)
        conv_gemm<false><<<512, 256, 0, stream>>>(x_pad, h_pad, Wt, b_conv, c_state, t);

    bn_out_kernel<<<2048, 256, 0, stream>>>(h_pad, gamma, beta, rmean, rvar, out);
}

// Round 7
// 378.001 us; speedup vs baseline: 1.1743x; 1.1743x over previous
//
#include <hip/hip_runtime.h>
#include <hip/hip_bf16.h>
#include <math.h>

typedef __attribute__((ext_vector_type(8))) short bf16x8;
typedef __attribute__((ext_vector_type(4))) float f32x4;

#define FRAME_PAD (66*66*128)   // padded NHWC frame elems (557568)

#define GLOAD_LDS16(g, l) \
    __builtin_amdgcn_global_load_lds((const __attribute__((address_space(1))) void*)(g), \
                                     (__attribute__((address_space(3))) void*)(l), 16, 0, 0)

#define WAITV6    asm volatile("s_waitcnt vmcnt(6)" ::: "memory")
#define WAITV0    asm volatile("s_waitcnt vmcnt(0)" ::: "memory")
#define LGKM0     asm volatile("s_waitcnt lgkmcnt(0)" ::: "memory")
#define SBAR      __builtin_amdgcn_s_barrier()
#define MEMPIN    asm volatile("" ::: "memory")

__device__ __forceinline__ float sigmoidf_(float x) { return 1.0f / (1.0f + __expf(-x)); }
__device__ __forceinline__ float tanhf_(float x) {
    x = fminf(fmaxf(x, -15.0f), 15.0f);
    float e = __expf(2.0f * x);
    return (e - 1.0f) / (e + 1.0f);
}
__device__ __forceinline__ float b2f_(short u) {
    unsigned int v = ((unsigned int)(unsigned short)u) << 16;
    return __builtin_bit_cast(float, v);
}
__device__ __forceinline__ short f2b_(float f) {
    __hip_bfloat16 hb = __float2bfloat16(f);
    return *reinterpret_cast<short*>(&hb);
}

// ---------- weights: W[oc][ic][tap] f32 -> Wt[tap][n'][ic] bf16, n' = c*4 + gate ----------
__global__ void wt_kernel(const float* __restrict__ w, __hip_bfloat16* __restrict__ wt)
{
    int idx = blockIdx.x * 256 + threadIdx.x;       // tap*131072 + n*256 + ic
    if (idx >= 9 * 512 * 256) return;
    int ic  = idx & 255;
    int n   = (idx >> 8) & 511;
    int tap = idx >> 17;
    int c = n >> 2, g = n & 3;                       // gate 0:i 1:f 2:o 3:g
    int oc = g * 128 + c;
    wt[idx] = __float2bfloat16(w[((size_t)oc * 256 + (size_t)ic) * 9 + tap]);
}

// ---------- zero the pad borders of all x and h frames ----------
__global__ void border_kernel(__hip_bfloat16* __restrict__ x_pad,
                              __hip_bfloat16* __restrict__ h_pad)
{
    const int fr = blockIdx.x;                        // 0..31 x, 32..63 h
    __hip_bfloat16* base = (fr < 32) ? x_pad + (size_t)fr * FRAME_PAD
                                     : h_pad + (size_t)(fr - 32) * FRAME_PAD;
    bf16x8 z = {};
    for (int u = threadIdx.x; u < 2112; u += 256) {
        int half = (u >= 1056) ? 1 : 0;
        int v = u - half * 1056;
        *(bf16x8*)(base + (size_t)(half * 65 * 66) * 128 + (size_t)v * 8) = z;
    }
    for (int u = threadIdx.x; u < 2048; u += 256) {
        int yy = 1 + (u >> 5);
        int r = u & 31;
        int side = r >> 4, c16 = r & 15;
        *(bf16x8*)(base + (size_t)(yy * 66 + side * 65) * 128 + (size_t)c16 * 8) = z;
    }
}

// ---------- x: NCHW f32 -> padded NHWC bf16 (vectorized, LDS stride-129 transpose) ----------
__global__ void xpose_kernel(const float* __restrict__ x, __hip_bfloat16* __restrict__ x_pad)
{
    __shared__ float tile[64][129];                  // [x][c]
    const int f = blockIdx.x >> 6;
    const int y = blockIdx.x & 63;
    const int tid = threadIdx.x;
    const float* src = x + (size_t)f * 524288 + (size_t)y * 64;
    #pragma unroll
    for (int it = 0; it < 8; ++it) {
        int c  = it * 16 + (tid >> 4);
        int xq = tid & 15;
        float4 v = *(const float4*)(src + (size_t)c * 4096 + xq * 4);
        tile[xq * 4 + 0][c] = v.x;
        tile[xq * 4 + 1][c] = v.y;
        tile[xq * 4 + 2][c] = v.z;
        tile[xq * 4 + 3][c] = v.w;
    }
    __syncthreads();
    __hip_bfloat16* dst = x_pad + (size_t)f * FRAME_PAD + (size_t)((y + 1) * 66 + 1) * 128;
    const int g = tid & 15;
    #pragma unroll
    for (int it = 0; it < 4; ++it) {
        int xr = it * 16 + (tid >> 4);
        bf16x8 o;
        #pragma unroll
        for (int e = 0; e < 8; ++e) o[e] = f2b_(tile[xr][g * 8 + e]);
        *(bf16x8*)(dst + (size_t)xr * 128 + g * 8) = o;
    }
}

// ---------- fused conv-GEMM + LSTM gates; m201-style phased pipeline, ring-3 ----------
// D[n'][m]: n' = c*4+gate (512, BN=128), m = spatial (16384, BM=256).
// K tiles of BK=64: T0 -> 18 (x only), else 36. Per K-tile: top {vmcnt(6); SBAR} then
// 2 phases, each {8 ds_read -> gloads -> SBAR -> lgkmcnt(0) -> setprio(1) 16 MFMA}.
// Ring-3 (S and W): stage(kt+2) targets the slot whose readers drained at kt-1's
// per-phase lgkm0 -> no mid-loop drains for staging. vmcnt never 0 in steady state.
template<bool T0>
__global__ __launch_bounds__(512, 2)
void conv_gemm(const __hip_bfloat16* __restrict__ x_pad,
               const __hip_bfloat16* __restrict__ h_pad,
               const __hip_bfloat16* __restrict__ wt,
               const float* __restrict__ bias,
               float* __restrict__ c_state, int t)
{
    __shared__ alignas(16) __hip_bfloat16 S_s[3][256 * 64];   // spatial ring, 3x32KB
    __shared__ alignas(16) __hip_bfloat16 W_s[3][128 * 64];   // weight ring,  3x16KB
    const int tid  = threadIdx.x;
    const int wv   = tid >> 6;
    const int lane = tid & 63;
    const int KT   = T0 ? 18 : 36;

    // XCD-chunked remap: each XCD owns 8 consecutive m-panels x all 4 n-blocks.
    const int F    = blockIdx.x;                 // 256 blocks
    const int tile = (F >> 3) + (F & 7) * 32;
    const int n0   = (tile & 3) * 128;
    const int mblk = tile >> 2;                  // 0..63
    const int b    = mblk >> 4;
    const int y0   = (mblk & 15) * 4;
    const int m0   = mblk * 256;

    const __hip_bfloat16* xf = x_pad + (size_t)(b * 8 + t) * FRAME_PAD;
    const __hip_bfloat16* hf = h_pad + (size_t)(b * 8 + (T0 ? 0 : t - 1)) * FRAME_PAD;

    // per-thread staging offsets (source pre-swizzled: q_src = q ^ (row&7), involution)
    int aOff[4], bOff[2];
    #pragma unroll
    for (int j = 0; j < 4; ++j) {
        int sid = j * 512 + tid;
        int row = sid >> 3;
        int q   = (sid & 7) ^ (row & 7);
        aOff[j] = ((y0 + (row >> 6)) * 66 + (row & 63)) * 128 + q * 8;
    }
    #pragma unroll
    for (int j = 0; j < 2; ++j) {
        int sid = j * 512 + tid;
        int row = sid >> 3;
        int q   = (sid & 7) ^ (row & 7);
        bOff[j] = (n0 + row) * 256 + q * 8;
    }

    auto STAGE_A = [&](__hip_bfloat16* Sl, int kt, int j0, int j1) {
        int tap, icq;
        const __hip_bfloat16* sb;
        if constexpr (T0) { tap = kt >> 1; icq = (kt & 1) * 64; sb = xf + icq; }
        else { tap = kt >> 2; icq = (kt & 3) * 64;
               sb = (icq < 128) ? (xf + icq) : (hf + (icq - 128)); }
        const int dy = tap / 3, dx = tap % 3;
        const __hip_bfloat16* a = sb + (dy * 66 + dx) * 128;
        for (int j = j0; j < j1; ++j)
            GLOAD_LDS16(a + aOff[j], Sl + (size_t)(j * 512 + tid) * 8);
    };
    auto STAGE_W = [&](__hip_bfloat16* Wl, int kt) {
        int tap, icq;
        if constexpr (T0) { tap = kt >> 1; icq = (kt & 1) * 64; }
        else { tap = kt >> 2; icq = (kt & 3) * 64; }
        const __hip_bfloat16* bsrc = wt + tap * 131072 + icq;
        #pragma unroll
        for (int j = 0; j < 2; ++j)
            GLOAD_LDS16(bsrc + bOff[j], Wl + (size_t)(j * 512 + tid) * 8);
    };

    // fragment read offsets (swizzled, lane-constant); K-half 1 = XOR 32 elems (64B)
    const int wm = wv >> 1, wn = wv & 1;
    const int fr = lane & 15, fq = lane >> 4;
    const int slot = (fq ^ (fr & 7)) * 8;
    const int sOff0 = (wm * 64 + fr) * 64 + slot, sOff1 = sOff0 ^ 32;
    const int wOff0 = (wn * 64 + fr) * 64 + slot, wOff1 = wOff0 ^ 32;

    f32x4 acc[4][4] = {};

    __hip_bfloat16 *Sr = &S_s[0][0], *Sn = &S_s[1][0], *Sf = &S_s[2][0];
    __hip_bfloat16 *Wr = &W_s[0][0], *Wn = &W_s[1][0], *Wf = &W_s[2][0];

    STAGE_A(Sr, 0, 0, 4); STAGE_W(Wr, 0);
    STAGE_A(Sn, 1, 0, 4); STAGE_W(Wn, 1);        // 12 loads/thread in flight

    #pragma unroll 1
    for (int kt = 0; kt < KT; ++kt) {
        // ---- K-tile gate: tile kt landed everywhere; kt+1 stays in flight ----
        if (kt < KT - 1) { WAITV6; } else { WAITV0; }
        SBAR;
        MEMPIN;

        bf16x8 w0[4], w1[4], s0[4], s1[4];
        // ---- phase 0: frags of K-half0 ; stage A-half0 of kt+2 ----
        #pragma unroll
        for (int ri = 0; ri < 4; ++ri) w0[ri] = *(const bf16x8*)(Wr + wOff0 + ri * 1024);
        #pragma unroll
        for (int ci = 0; ci < 4; ++ci) s0[ci] = *(const bf16x8*)(Sr + sOff0 + ci * 1024);
        if (kt < KT - 2) STAGE_A(Sf, kt + 2, 0, 2);
        SBAR;
        LGKM0;
        __builtin_amdgcn_s_setprio(1);
        #pragma unroll
        for (int ri = 0; ri < 4; ++ri)
            #pragma unroll
            for (int ci = 0; ci < 4; ++ci)
                acc[ri][ci] = __builtin_amdgcn_mfma_f32_16x16x32_bf16(w0[ri], s0[ci], acc[ri][ci], 0, 0, 0);
        __builtin_amdgcn_s_setprio(0);
        SBAR;
        MEMPIN;
        // ---- phase 1: frags of K-half1 ; stage A-half1 + W of kt+2 ----
        #pragma unroll
        for (int ri = 0; ri < 4; ++ri) w1[ri] = *(const bf16x8*)(Wr + wOff1 + ri * 1024);
        #pragma unroll
        for (int ci = 0; ci < 4; ++ci) s1[ci] = *(const bf16x8*)(Sr + sOff1 + ci * 1024);
        if (kt < KT - 2) { STAGE_A(Sf, kt + 2, 2, 4); STAGE_W(Wf, kt + 2); }
        SBAR;
        LGKM0;
        __builtin_amdgcn_s_setprio(1);
        #pragma unroll
        for (int ri = 0; ri < 4; ++ri)
            #pragma unroll
            for (int ci = 0; ci < 4; ++ci)
                acc[ri][ci] = __builtin_amdgcn_mfma_f32_16x16x32_bf16(w1[ri], s1[ci], acc[ri][ci], 0, 0, 0);
        __builtin_amdgcn_s_setprio(0);

        __hip_bfloat16* tp = Sr; Sr = Sn; Sn = Sf; Sf = tp;
        __hip_bfloat16* tw = Wr; Wr = Wn; Wn = Wf; Wf = tw;
    }

    // ---------- fused LSTM gate epilogue (identical math to validated rounds) ----------
    const int c0    = (n0 >> 2) + wn * 16;
    const int mcol0 = m0 + wm * 64 + fr;
    __hip_bfloat16* hout = (__hip_bfloat16*)h_pad + (size_t)(b * 8 + t) * FRAME_PAD;
    #pragma unroll
    for (int ri = 0; ri < 4; ++ri) {
        const int c = c0 + ri * 4 + fq;
        const float bi  = bias[c];
        const float bfv = bias[128 + c];
        const float bo  = bias[256 + c];
        const float bg  = bias[384 + c];
        float* csrow = c_state + (size_t)c * 16384;
        #pragma unroll
        for (int ci = 0; ci < 4; ++ci) {
            const int m = mcol0 + ci * 16;
            const int s = m & 4095;
            const float cold = T0 ? 0.0f : csrow[m];
            const float zi = acc[ri][ci][0] + bi;
            const float zf = acc[ri][ci][1] + bfv;
            const float zo = acc[ri][ci][2] + bo;
            const float zg = acc[ri][ci][3] + bg;
            const float cn = sigmoidf_(zf) * cold + sigmoidf_(zi) * tanhf_(zg);
            const float h  = sigmoidf_(zo) * tanhf_(cn);
            csrow[m] = cn;
            hout[(size_t)(((s >> 6) + 1) * 66 + (s & 63) + 1) * 128 + c] = __float2bfloat16(h);
        }
    }
}

// ---------- final: padded-NHWC bf16 h -> NCHW f32 out, BN(eval)+ReLU fused in load ----------
__global__ void bn_out_kernel(const __hip_bfloat16* __restrict__ h_pad,
                              const float* __restrict__ gamma, const float* __restrict__ beta,
                              const float* __restrict__ rmean, const float* __restrict__ rvar,
                              float* __restrict__ out)
{
    __shared__ float tile[64][129];                  // [x][c], post-BN values
    __shared__ float sc_s[128], sh_s[128];
    const int fo  = blockIdx.x >> 6;                 // frame = b*8+t = h slot
    const int y   = blockIdx.x & 63;
    const int tid = threadIdx.x;
    if (tid < 128) {
        float sc = gamma[tid] * rsqrtf(rvar[tid] + 1e-5f);
        sc_s[tid] = sc;
        sh_s[tid] = beta[tid] - rmean[tid] * sc;
    }
    __syncthreads();
    const __hip_bfloat16* src =
        h_pad + (size_t)fo * FRAME_PAD + (size_t)((y + 1) * 66 + 1) * 128;
    const int g = tid & 15;
    float sc[8], sh[8];
    #pragma unroll
    for (int e = 0; e < 8; ++e) { sc[e] = sc_s[g * 8 + e]; sh[e] = sh_s[g * 8 + e]; }
    #pragma unroll
    for (int it = 0; it < 4; ++it) {
        int xr = it * 16 + (tid >> 4);
        bf16x8 v = *(const bf16x8*)(src + (size_t)xr * 128 + g * 8);
        #pragma unroll
        for (int e = 0; e < 8; ++e)
            tile[xr][g * 8 + e] = fmaxf(b2f_(v[e]) * sc[e] + sh[e], 0.0f);
    }
    __syncthreads();
    float* dst = out + (size_t)fo * 524288 + (size_t)y * 64;
    #pragma unroll
    for (int it = 0; it < 8; ++it) {
        int c  = it * 16 + (tid >> 4);
        int xq = tid & 15;
        float4 o;
        o.x = tile[xq * 4 + 0][c];
        o.y = tile[xq * 4 + 1][c];
        o.z = tile[xq * 4 + 2][c];
        o.w = tile[xq * 4 + 3][c];
        *(float4*)(dst + (size_t)c * 4096 + xq * 4) = o;
    }
}

extern "C" void kernel_launch(void* const* d_in, const int* in_sizes, int n_in,
                              void* d_out, int out_size, void* d_ws, size_t ws_size,
                              hipStream_t stream)
{
    const float* x      = (const float*)d_in[0];
    const float* w_conv = (const float*)d_in[1];
    const float* b_conv = (const float*)d_in[2];
    const float* gamma  = (const float*)d_in[3];
    const float* beta   = (const float*)d_in[4];
    const float* rmean  = (const float*)d_in[5];
    const float* rvar   = (const float*)d_in[6];
    float* out = (float*)d_out;

    // workspace layout (bytes)
    //   Wt      @ 0          : 9*512*256*2    = 2,359,296
    //   x_pad   @ 2359296    : 32*66*66*128*2 = 35,684,352
    //   h_pad   @ 38043648   : 32*66*66*128*2 = 35,684,352   (slot b*8+t = h after step t)
    //   c_state @ 73728000   : 128*16384*4    = 8,388,608    ([c][m]; written before read)
    //   total 82,116,608
    if (ws_size < 82116608u) return;

    char* ws = (char*)d_ws;
    __hip_bfloat16* Wt    = (__hip_bfloat16*)(ws);
    __hip_bfloat16* x_pad = (__hip_bfloat16*)(ws + 2359296);
    __hip_bfloat16* h_pad = (__hip_bfloat16*)(ws + 38043648);
    float* c_state        = (float*)(ws + 73728000);

    wt_kernel<<<4608, 256, 0, stream>>>(w_conv, Wt);
    xpose_kernel<<<2048, 256, 0, stream>>>(x, x_pad);
    border_kernel<<<64, 256, 0, stream>>>(x_pad, h_pad);

    conv_gemm<true><<<256, 512, 0, stream>>>(x_pad, h_pad, Wt, b_conv, c_state, 0);
    for (int t = 1; t < 8; ++t)
        conv_gemm<false><<<256, 512, 0, stream>>>(x_pad, h_pad, Wt, b_conv, c_state, t);

    bn_out_kernel<<<2048, 256, 0, stream>>>(h_pad, gamma, beta, rmean, rvar, out);
}

// Round 8
// 354.129 us; speedup vs baseline: 1.2535x; 1.0674x over previous
//
#include <hip/hip_runtime.h>
#include <hip/hip_bf16.h>
#include <math.h>

typedef __attribute__((ext_vector_type(8))) short bf16x8;
typedef __attribute__((ext_vector_type(4))) float f32x4;

#define FRAME_PAD (66*66*128)   // padded NHWC frame elems (557568)

#define GLOAD_LDS16(g, l) \
    __builtin_amdgcn_global_load_lds((const __attribute__((address_space(1))) void*)(g), \
                                     (__attribute__((address_space(3))) void*)(l), 16, 0, 0)

#define WAITV6    asm volatile("s_waitcnt vmcnt(6)" ::: "memory")
#define WAITV0    asm volatile("s_waitcnt vmcnt(0)" ::: "memory")
#define WAITLGKM0 asm volatile("s_waitcnt lgkmcnt(0)" ::: "memory")
#define SBAR      __builtin_amdgcn_s_barrier()

__device__ __forceinline__ float sigmoidf_(float x) { return 1.0f / (1.0f + __expf(-x)); }
__device__ __forceinline__ float tanhf_(float x) {
    x = fminf(fmaxf(x, -15.0f), 15.0f);
    float e = __expf(2.0f * x);
    return (e - 1.0f) / (e + 1.0f);
}
__device__ __forceinline__ float b2f_(short u) {
    unsigned int v = ((unsigned int)(unsigned short)u) << 16;
    return __builtin_bit_cast(float, v);
}
__device__ __forceinline__ short f2b_(float f) {
    __hip_bfloat16 hb = __float2bfloat16(f);
    return *reinterpret_cast<short*>(&hb);
}

// ---------- weights: W[oc][ic][tap] f32 -> Wt[tap][n'][ic] bf16, n' = c*4 + gate ----------
__global__ void wt_kernel(const float* __restrict__ w, __hip_bfloat16* __restrict__ wt)
{
    int idx = blockIdx.x * 256 + threadIdx.x;       // tap*131072 + n*256 + ic
    if (idx >= 9 * 512 * 256) return;
    int ic  = idx & 255;
    int n   = (idx >> 8) & 511;
    int tap = idx >> 17;
    int c = n >> 2, g = n & 3;                       // gate 0:i 1:f 2:o 3:g
    int oc = g * 128 + c;
    wt[idx] = __float2bfloat16(w[((size_t)oc * 256 + (size_t)ic) * 9 + tap]);
}

// ---------- zero the pad borders of all x and h frames ----------
__global__ void border_kernel(__hip_bfloat16* __restrict__ x_pad,
                              __hip_bfloat16* __restrict__ h_pad)
{
    const int fr = blockIdx.x;                        // 0..31 x, 32..63 h
    __hip_bfloat16* base = (fr < 32) ? x_pad + (size_t)fr * FRAME_PAD
                                     : h_pad + (size_t)(fr - 32) * FRAME_PAD;
    bf16x8 z = {};
    for (int u = threadIdx.x; u < 2112; u += 256) {
        int half = (u >= 1056) ? 1 : 0;
        int v = u - half * 1056;
        *(bf16x8*)(base + (size_t)(half * 65 * 66) * 128 + (size_t)v * 8) = z;
    }
    for (int u = threadIdx.x; u < 2048; u += 256) {
        int yy = 1 + (u >> 5);
        int r = u & 31;
        int side = r >> 4, c16 = r & 15;
        *(bf16x8*)(base + (size_t)(yy * 66 + side * 65) * 128 + (size_t)c16 * 8) = z;
    }
}

// ---------- x: NCHW f32 -> padded NHWC bf16 (vectorized, LDS stride-129 transpose) ----------
__global__ void xpose_kernel(const float* __restrict__ x, __hip_bfloat16* __restrict__ x_pad)
{
    __shared__ float tile[64][129];                  // [x][c]
    const int f = blockIdx.x >> 6;
    const int y = blockIdx.x & 63;
    const int tid = threadIdx.x;
    const float* src = x + (size_t)f * 524288 + (size_t)y * 64;
    #pragma unroll
    for (int it = 0; it < 8; ++it) {
        int c  = it * 16 + (tid >> 4);
        int xq = tid & 15;
        float4 v = *(const float4*)(src + (size_t)c * 4096 + xq * 4);
        tile[xq * 4 + 0][c] = v.x;
        tile[xq * 4 + 1][c] = v.y;
        tile[xq * 4 + 2][c] = v.z;
        tile[xq * 4 + 3][c] = v.w;
    }
    __syncthreads();
    __hip_bfloat16* dst = x_pad + (size_t)f * FRAME_PAD + (size_t)((y + 1) * 66 + 1) * 128;
    const int g = tid & 15;
    #pragma unroll
    for (int it = 0; it < 4; ++it) {
        int xr = it * 16 + (tid >> 4);
        bf16x8 o;
        #pragma unroll
        for (int e = 0; e < 8; ++e) o[e] = f2b_(tile[xr][g * 8 + e]);
        *(bf16x8*)(dst + (size_t)xr * 128 + g * 8) = o;
    }
}

// ---------- fused conv-GEMM + LSTM gates + BN/ReLU output; R3's validated pipeline ----------
// D[n'][m]: n' = c*4+gate (512, BN=128), m = spatial (16384, BM=256).
// K tiles of BK=64: T0 -> 18 (x only), else 36. Dbuf-2; per ITER: {vmcnt(6); SBAR;
// read all 16 frags; MFMA half0; lgkm0+sched_barrier; SBAR; stage kt+2 into same
// buffer (fully consumed); MFMA half1}. vmcnt never 0 in steady state. This exact
// structure measured 47.0 us (R3) -- best of 6 schedule variants tried (47..61).
template<bool T0>
__global__ __launch_bounds__(512, 2)
void conv_gemm(const __hip_bfloat16* __restrict__ x_pad,
               const __hip_bfloat16* __restrict__ h_pad,
               const __hip_bfloat16* __restrict__ wt,
               const float* __restrict__ bias,
               const float* __restrict__ gamma, const float* __restrict__ beta,
               const float* __restrict__ rmean, const float* __restrict__ rvar,
               float* __restrict__ c_state, float* __restrict__ out, int t)
{
    __shared__ alignas(16) __hip_bfloat16 S_s[2][256 * 64];   // spatial dbuf, 2x32KB
    __shared__ alignas(16) __hip_bfloat16 W_s[2][128 * 64];   // weight dbuf,  2x16KB
    const int tid  = threadIdx.x;
    const int wv   = tid >> 6;
    const int lane = tid & 63;
    const int KT   = T0 ? 18 : 36;

    // XCD-chunked remap: each XCD owns 8 consecutive m-panels x all 4 n-blocks.
    const int F    = blockIdx.x;                 // 256 blocks
    const int tile = (F >> 3) + (F & 7) * 32;
    const int n0   = (tile & 3) * 128;
    const int mblk = tile >> 2;                  // 0..63
    const int b    = mblk >> 4;
    const int y0   = (mblk & 15) * 4;
    const int m0   = mblk * 256;

    const __hip_bfloat16* xf = x_pad + (size_t)(b * 8 + t) * FRAME_PAD;
    const __hip_bfloat16* hf = T0 ? xf
                                  : h_pad + (size_t)(b * 8 + t - 1) * FRAME_PAD;

    // per-thread staging offsets (source pre-swizzled: q_src = q ^ (row&7), involution)
    int aOff[4], bOff[2];
    #pragma unroll
    for (int j = 0; j < 4; ++j) {
        int sid = j * 512 + tid;
        int row = sid >> 3;
        int q   = (sid & 7) ^ (row & 7);
        aOff[j] = ((y0 + (row >> 6)) * 66 + (row & 63)) * 128 + q * 8;
    }
    #pragma unroll
    for (int j = 0; j < 2; ++j) {
        int sid = j * 512 + tid;
        int row = sid >> 3;
        int q   = (sid & 7) ^ (row & 7);
        bOff[j] = (n0 + row) * 256 + q * 8;
    }

    auto STAGE = [&](__hip_bfloat16* Sl, __hip_bfloat16* Wl, int kt) {
        int tap, icq;
        const __hip_bfloat16* sb;
        if constexpr (T0) { tap = kt >> 1; icq = (kt & 1) * 64; sb = xf + icq; }
        else { tap = kt >> 2; icq = (kt & 3) * 64;
               sb = (icq < 128) ? (xf + icq) : (hf + (icq - 128)); }
        const int dy = tap / 3, dx = tap % 3;
        const __hip_bfloat16* a = sb + (dy * 66 + dx) * 128;
        #pragma unroll
        for (int j = 0; j < 4; ++j)
            GLOAD_LDS16(a + aOff[j], Sl + (size_t)(j * 512 + tid) * 8);
        const __hip_bfloat16* bsrc = wt + tap * 131072 + icq;
        #pragma unroll
        for (int j = 0; j < 2; ++j)
            GLOAD_LDS16(bsrc + bOff[j], Wl + (size_t)(j * 512 + tid) * 8);
    };

    // fragment read offsets (swizzled, lane-constant); K-half 1 = XOR 32 elems (64B)
    const int wm = wv >> 1, wn = wv & 1;
    const int fr = lane & 15, fq = lane >> 4;
    const int slot = (fq ^ (fr & 7)) * 8;
    const int sOff0 = (wm * 64 + fr) * 64 + slot, sOff1 = sOff0 ^ 32;
    const int wOff0 = (wn * 64 + fr) * 64 + slot, wOff1 = wOff0 ^ 32;

    f32x4 acc[4][4] = {};

    auto ITER = [&](__hip_bfloat16* Sb, __hip_bfloat16* Wb, int kt) {
        if (kt < KT - 1) { WAITV6; } else { WAITV0; }   // tile kt landed; next in flight
        SBAR;
        bf16x8 w0[4], w1[4], s0[4], s1[4];
        #pragma unroll
        for (int ri = 0; ri < 4; ++ri) {
            w0[ri] = *(const bf16x8*)(Wb + wOff0 + ri * 1024);
            w1[ri] = *(const bf16x8*)(Wb + wOff1 + ri * 1024);
        }
        #pragma unroll
        for (int ci = 0; ci < 4; ++ci) {
            s0[ci] = *(const bf16x8*)(Sb + sOff0 + ci * 1024);
            s1[ci] = *(const bf16x8*)(Sb + sOff1 + ci * 1024);
        }
        __builtin_amdgcn_s_setprio(1);
        #pragma unroll
        for (int ri = 0; ri < 4; ++ri)
            #pragma unroll
            for (int ci = 0; ci < 4; ++ci)
                acc[ri][ci] = __builtin_amdgcn_mfma_f32_16x16x32_bf16(w0[ri], s0[ci], acc[ri][ci], 0, 0, 0);
        __builtin_amdgcn_s_setprio(0);
        WAITLGKM0;                               // all 16 reads hardware-complete
        __builtin_amdgcn_sched_barrier(0);       // rule 18: pin the boundary
        SBAR;                                    // all waves done reading this buffer
        if (kt < KT - 2) STAGE(Sb, Wb, kt + 2);  // overwrite now safe; loads fly ahead
        __builtin_amdgcn_s_setprio(1);
        #pragma unroll
        for (int ri = 0; ri < 4; ++ri)
            #pragma unroll
            for (int ci = 0; ci < 4; ++ci)
                acc[ri][ci] = __builtin_amdgcn_mfma_f32_16x16x32_bf16(w1[ri], s1[ci], acc[ri][ci], 0, 0, 0);
        __builtin_amdgcn_s_setprio(0);
    };

    STAGE(S_s[0], W_s[0], 0);
    STAGE(S_s[1], W_s[1], 1);                    // 12 loads/thread in flight
    #pragma unroll 1
    for (int kt = 0; kt < KT; kt += 2) {
        ITER(S_s[0], W_s[0], kt);
        ITER(S_s[1], W_s[1], kt + 1);
    }

    // ---------- fused LSTM gates + BN(eval)+ReLU output epilogue ----------
    const int c0    = (n0 >> 2) + wn * 16;
    const int mcol0 = m0 + wm * 64 + fr;
    __hip_bfloat16* hout = (__hip_bfloat16*)h_pad + (size_t)(b * 8 + t) * FRAME_PAD;
    float* oframe = out + (size_t)(b * 8 + t) * 524288;
    #pragma unroll
    for (int ri = 0; ri < 4; ++ri) {
        const int c = c0 + ri * 4 + fq;
        const float bi  = bias[c];
        const float bfv = bias[128 + c];
        const float bo  = bias[256 + c];
        const float bg  = bias[384 + c];
        const float scv = gamma[c] * rsqrtf(rvar[c] + 1e-5f);
        const float shv = beta[c] - rmean[c] * scv;
        float* csrow = c_state + (size_t)c * 16384;
        #pragma unroll
        for (int ci = 0; ci < 4; ++ci) {
            const int m = mcol0 + ci * 16;
            const int s = m & 4095;
            const float cold = T0 ? 0.0f : csrow[m];
            const float zi = acc[ri][ci][0] + bi;
            const float zf = acc[ri][ci][1] + bfv;
            const float zo = acc[ri][ci][2] + bo;
            const float zg = acc[ri][ci][3] + bg;
            const float cn = sigmoidf_(zf) * cold + sigmoidf_(zi) * tanhf_(zg);
            const float h  = sigmoidf_(zo) * tanhf_(cn);
            csrow[m] = cn;
            hout[(size_t)(((s >> 6) + 1) * 66 + (s & 63) + 1) * 128 + c] = __float2bfloat16(h);
            oframe[(size_t)c * 4096 + s] = fmaxf(h * scv + shv, 0.0f);
        }
    }
}

extern "C" void kernel_launch(void* const* d_in, const int* in_sizes, int n_in,
                              void* d_out, int out_size, void* d_ws, size_t ws_size,
                              hipStream_t stream)
{
    const float* x      = (const float*)d_in[0];
    const float* w_conv = (const float*)d_in[1];
    const float* b_conv = (const float*)d_in[2];
    const float* gamma  = (const float*)d_in[3];
    const float* beta   = (const float*)d_in[4];
    const float* rmean  = (const float*)d_in[5];
    const float* rvar   = (const float*)d_in[6];
    float* out = (float*)d_out;

    // workspace layout (bytes)
    //   Wt      @ 0          : 9*512*256*2    = 2,359,296
    //   x_pad   @ 2359296    : 32*66*66*128*2 = 35,684,352
    //   h_pad   @ 38043648   : 32*66*66*128*2 = 35,684,352   (slot b*8+t = h after step t)
    //   c_state @ 73728000   : 128*16384*4    = 8,388,608    ([c][m]; written before read)
    //   total 82,116,608
    if (ws_size < 82116608u) return;

    char* ws = (char*)d_ws;
    __hip_bfloat16* Wt    = (__hip_bfloat16*)(ws);
    __hip_bfloat16* x_pad = (__hip_bfloat16*)(ws + 2359296);
    __hip_bfloat16* h_pad = (__hip_bfloat16*)(ws + 38043648);
    float* c_state        = (float*)(ws + 73728000);

    wt_kernel<<<4608, 256, 0, stream>>>(w_conv, Wt);
    xpose_kernel<<<2048, 256, 0, stream>>>(x, x_pad);
    border_kernel<<<64, 256, 0, stream>>>(x_pad, h_pad);

    conv_gemm<true><<<256, 512, 0, stream>>>(x_pad, h_pad, Wt, b_conv,
                                             gamma, beta, rmean, rvar, c_state, out, 0);
    for (int t = 1; t < 8; ++t)
        conv_gemm<false><<<256, 512, 0, stream>>>(x_pad, h_pad, Wt, b_conv,
                                                  gamma, beta, rmean, rvar, c_state, out, t);
}

// Round 9
// 351.978 us; speedup vs baseline: 1.2611x; 1.0061x over previous
//
#include <hip/hip_runtime.h>
#include <hip/hip_bf16.h>
#include <math.h>

typedef __attribute__((ext_vector_type(8))) short bf16x8;
typedef __attribute__((ext_vector_type(4))) float f32x4;

#define FRAME_PAD (66*66*128)   // padded NHWC frame elems (557568)

#define GLOAD_LDS16(g, l) \
    __builtin_amdgcn_global_load_lds((const __attribute__((address_space(1))) void*)(g), \
                                     (__attribute__((address_space(3))) void*)(l), 16, 0, 0)

#define WAITV8    asm volatile("s_waitcnt vmcnt(8)" ::: "memory")
#define WAITV0    asm volatile("s_waitcnt vmcnt(0)" ::: "memory")
#define WAITLGKM0 asm volatile("s_waitcnt lgkmcnt(0)" ::: "memory")
#define SBAR      __builtin_amdgcn_s_barrier()

__device__ __forceinline__ float sigmoidf_(float x) { return 1.0f / (1.0f + __expf(-x)); }
__device__ __forceinline__ float tanhf_(float x) {
    x = fminf(fmaxf(x, -15.0f), 15.0f);
    float e = __expf(2.0f * x);
    return (e - 1.0f) / (e + 1.0f);
}
__device__ __forceinline__ float b2f_(short u) {
    unsigned int v = ((unsigned int)(unsigned short)u) << 16;
    return __builtin_bit_cast(float, v);
}
__device__ __forceinline__ short f2b_(float f) {
    __hip_bfloat16 hb = __float2bfloat16(f);
    return *reinterpret_cast<short*>(&hb);
}

// ---------- weights: W[oc][ic][tap] f32 -> Wt[tap][n'][ic] bf16, n' = c*4 + gate ----------
__global__ void wt_kernel(const float* __restrict__ w, __hip_bfloat16* __restrict__ wt)
{
    int idx = blockIdx.x * 256 + threadIdx.x;       // tap*131072 + n*256 + ic
    if (idx >= 9 * 512 * 256) return;
    int ic  = idx & 255;
    int n   = (idx >> 8) & 511;
    int tap = idx >> 17;
    int c = n >> 2, g = n & 3;                       // gate 0:i 1:f 2:o 3:g
    int oc = g * 128 + c;
    wt[idx] = __float2bfloat16(w[((size_t)oc * 256 + (size_t)ic) * 9 + tap]);
}

// ---------- zero the pad borders of all x and h frames ----------
__global__ void border_kernel(__hip_bfloat16* __restrict__ x_pad,
                              __hip_bfloat16* __restrict__ h_pad)
{
    const int fr = blockIdx.x;                        // 0..31 x, 32..63 h
    __hip_bfloat16* base = (fr < 32) ? x_pad + (size_t)fr * FRAME_PAD
                                     : h_pad + (size_t)(fr - 32) * FRAME_PAD;
    bf16x8 z = {};
    for (int u = threadIdx.x; u < 2112; u += 256) {
        int half = (u >= 1056) ? 1 : 0;
        int v = u - half * 1056;
        *(bf16x8*)(base + (size_t)(half * 65 * 66) * 128 + (size_t)v * 8) = z;
    }
    for (int u = threadIdx.x; u < 2048; u += 256) {
        int yy = 1 + (u >> 5);
        int r = u & 31;
        int side = r >> 4, c16 = r & 15;
        *(bf16x8*)(base + (size_t)(yy * 66 + side * 65) * 128 + (size_t)c16 * 8) = z;
    }
}

// ---------- x: NCHW f32 -> padded NHWC bf16 (vectorized, LDS stride-129 transpose) ----------
__global__ void xpose_kernel(const float* __restrict__ x, __hip_bfloat16* __restrict__ x_pad)
{
    __shared__ float tile[64][129];                  // [x][c]
    const int f = blockIdx.x >> 6;
    const int y = blockIdx.x & 63;
    const int tid = threadIdx.x;
    const float* src = x + (size_t)f * 524288 + (size_t)y * 64;
    #pragma unroll
    for (int it = 0; it < 8; ++it) {
        int c  = it * 16 + (tid >> 4);
        int xq = tid & 15;
        float4 v = *(const float4*)(src + (size_t)c * 4096 + xq * 4);
        tile[xq * 4 + 0][c] = v.x;
        tile[xq * 4 + 1][c] = v.y;
        tile[xq * 4 + 2][c] = v.z;
        tile[xq * 4 + 3][c] = v.w;
    }
    __syncthreads();
    __hip_bfloat16* dst = x_pad + (size_t)f * FRAME_PAD + (size_t)((y + 1) * 66 + 1) * 128;
    const int g = tid & 15;
    #pragma unroll
    for (int it = 0; it < 4; ++it) {
        int xr = it * 16 + (tid >> 4);
        bf16x8 o;
        #pragma unroll
        for (int e = 0; e < 8; ++e) o[e] = f2b_(tile[xr][g * 8 + e]);
        *(bf16x8*)(dst + (size_t)xr * 128 + g * 8) = o;
    }
}

// ---------- fused conv-GEMM + LSTM gates + BN/ReLU; R3 ITER rhythm @ 2 blocks/CU ----------
// D[n'][m]: n' = c*4+gate (512, BN=128), m = spatial (16384, BM=128) -> grid 512,
// dbuf-2 LDS = 64KB -> 2 blocks co-resident per CU (isolates m114 co-residency at
// R3's exact per-wave rhythm: BK=64, 16 frag-reads + 32 MFMA per barrier window,
// counted vmcnt gate -- same per-work LDS traffic as the 256x128/8-wave config).
template<bool T0>
__global__ __launch_bounds__(256, 2)
void conv_gemm(const __hip_bfloat16* __restrict__ x_pad,
               const __hip_bfloat16* __restrict__ h_pad,
               const __hip_bfloat16* __restrict__ wt,
               const float* __restrict__ bias,
               const float* __restrict__ gamma, const float* __restrict__ beta,
               const float* __restrict__ rmean, const float* __restrict__ rvar,
               float* __restrict__ c_state, float* __restrict__ out, int t)
{
    __shared__ alignas(16) __hip_bfloat16 S_s[2][128 * 64];   // spatial dbuf, 2x16KB
    __shared__ alignas(16) __hip_bfloat16 W_s[2][128 * 64];   // weight dbuf,  2x16KB
    const int tid  = threadIdx.x;
    const int wv   = tid >> 6;
    const int lane = tid & 63;
    const int KT   = T0 ? 18 : 36;

    // XCD-chunked remap: each XCD owns 64 consecutive tiles (16 m-panels x 4 n-blocks).
    const int F    = blockIdx.x;                 // 512 blocks
    const int tile = (F >> 3) + (F & 7) * 64;
    const int n0   = (tile & 3) * 128;
    const int mblk = tile >> 2;                  // 0..127
    const int b    = mblk >> 5;
    const int y0   = (mblk & 31) * 2;
    const int m0   = mblk * 128;

    const __hip_bfloat16* xf = x_pad + (size_t)(b * 8 + t) * FRAME_PAD;
    const __hip_bfloat16* hf = T0 ? xf
                                  : h_pad + (size_t)(b * 8 + t - 1) * FRAME_PAD;

    // per-thread staging offsets (source pre-swizzled: q_src = q ^ (row&7), involution)
    int aOff[4], bOff[4];
    #pragma unroll
    for (int j = 0; j < 4; ++j) {
        int sid = j * 256 + tid;
        int row = sid >> 3;
        int q   = (sid & 7) ^ (row & 7);
        aOff[j] = ((y0 + (row >> 6)) * 66 + (row & 63)) * 128 + q * 8;
        bOff[j] = (n0 + row) * 256 + q * 8;
    }

    auto STAGE = [&](__hip_bfloat16* Sl, __hip_bfloat16* Wl, int kt) {
        int tap, icq;
        const __hip_bfloat16* sb;
        if constexpr (T0) { tap = kt >> 1; icq = (kt & 1) * 64; sb = xf + icq; }
        else { tap = kt >> 2; icq = (kt & 3) * 64;
               sb = (icq < 128) ? (xf + icq) : (hf + (icq - 128)); }
        const int dy = tap / 3, dx = tap % 3;
        const __hip_bfloat16* a = sb + (dy * 66 + dx) * 128;
        #pragma unroll
        for (int j = 0; j < 4; ++j)
            GLOAD_LDS16(a + aOff[j], Sl + (size_t)(j * 256 + tid) * 8);
        const __hip_bfloat16* bsrc = wt + tap * 131072 + icq;
        #pragma unroll
        for (int j = 0; j < 4; ++j)
            GLOAD_LDS16(bsrc + bOff[j], Wl + (size_t)(j * 256 + tid) * 8);
    };

    // fragment read offsets (swizzled, lane-constant); K-half 1 = XOR 32 elems (64B)
    const int wm = wv >> 1, wn = wv & 1;
    const int fr = lane & 15, fq = lane >> 4;
    const int slot = (fq ^ (fr & 7)) * 8;
    const int sOff0 = (wm * 64 + fr) * 64 + slot, sOff1 = sOff0 ^ 32;
    const int wOff0 = (wn * 64 + fr) * 64 + slot, wOff1 = wOff0 ^ 32;

    f32x4 acc[4][4] = {};

    auto ITER = [&](__hip_bfloat16* Sb, __hip_bfloat16* Wb, int kt) {
        if (kt < KT - 1) { WAITV8; } else { WAITV0; }   // tile kt landed; next in flight
        SBAR;
        bf16x8 w0[4], w1[4], s0[4], s1[4];
        #pragma unroll
        for (int ri = 0; ri < 4; ++ri) {
            w0[ri] = *(const bf16x8*)(Wb + wOff0 + ri * 1024);
            w1[ri] = *(const bf16x8*)(Wb + wOff1 + ri * 1024);
        }
        #pragma unroll
        for (int ci = 0; ci < 4; ++ci) {
            s0[ci] = *(const bf16x8*)(Sb + sOff0 + ci * 1024);
            s1[ci] = *(const bf16x8*)(Sb + sOff1 + ci * 1024);
        }
        __builtin_amdgcn_s_setprio(1);
        #pragma unroll
        for (int ri = 0; ri < 4; ++ri)
            #pragma unroll
            for (int ci = 0; ci < 4; ++ci)
                acc[ri][ci] = __builtin_amdgcn_mfma_f32_16x16x32_bf16(w0[ri], s0[ci], acc[ri][ci], 0, 0, 0);
        __builtin_amdgcn_s_setprio(0);
        WAITLGKM0;                               // all 16 reads hardware-complete
        __builtin_amdgcn_sched_barrier(0);       // rule 18: pin the boundary
        SBAR;                                    // all waves done reading this buffer
        if (kt < KT - 2) STAGE(Sb, Wb, kt + 2);  // overwrite now safe; loads fly ahead
        __builtin_amdgcn_s_setprio(1);
        #pragma unroll
        for (int ri = 0; ri < 4; ++ri)
            #pragma unroll
            for (int ci = 0; ci < 4; ++ci)
                acc[ri][ci] = __builtin_amdgcn_mfma_f32_16x16x32_bf16(w1[ri], s1[ci], acc[ri][ci], 0, 0, 0);
        __builtin_amdgcn_s_setprio(0);
    };

    STAGE(S_s[0], W_s[0], 0);
    STAGE(S_s[1], W_s[1], 1);                    // 16 loads/thread in flight
    #pragma unroll 1
    for (int kt = 0; kt < KT; kt += 2) {
        ITER(S_s[0], W_s[0], kt);
        ITER(S_s[1], W_s[1], kt + 1);
    }

    // ---------- fused LSTM gates + BN(eval)+ReLU output epilogue ----------
    const int c0    = (n0 >> 2) + wn * 16;
    const int mcol0 = m0 + wm * 64 + fr;
    __hip_bfloat16* hout = (__hip_bfloat16*)h_pad + (size_t)(b * 8 + t) * FRAME_PAD;
    float* oframe = out + (size_t)(b * 8 + t) * 524288;
    #pragma unroll
    for (int ri = 0; ri < 4; ++ri) {
        const int c = c0 + ri * 4 + fq;
        const float bi  = bias[c];
        const float bfv = bias[128 + c];
        const float bo  = bias[256 + c];
        const float bg  = bias[384 + c];
        const float scv = gamma[c] * rsqrtf(rvar[c] + 1e-5f);
        const float shv = beta[c] - rmean[c] * scv;
        float* csrow = c_state + (size_t)c * 16384;
        #pragma unroll
        for (int ci = 0; ci < 4; ++ci) {
            const int m = mcol0 + ci * 16;
            const int s = m & 4095;
            const float cold = T0 ? 0.0f : csrow[m];
            const float zi = acc[ri][ci][0] + bi;
            const float zf = acc[ri][ci][1] + bfv;
            const float zo = acc[ri][ci][2] + bo;
            const float zg = acc[ri][ci][3] + bg;
            const float cn = sigmoidf_(zf) * cold + sigmoidf_(zi) * tanhf_(zg);
            const float h  = sigmoidf_(zo) * tanhf_(cn);
            csrow[m] = cn;
            hout[(size_t)(((s >> 6) + 1) * 66 + (s & 63) + 1) * 128 + c] = __float2bfloat16(h);
            oframe[(size_t)c * 4096 + s] = fmaxf(h * scv + shv, 0.0f);
        }
    }
}

extern "C" void kernel_launch(void* const* d_in, const int* in_sizes, int n_in,
                              void* d_out, int out_size, void* d_ws, size_t ws_size,
                              hipStream_t stream)
{
    const float* x      = (const float*)d_in[0];
    const float* w_conv = (const float*)d_in[1];
    const float* b_conv = (const float*)d_in[2];
    const float* gamma  = (const float*)d_in[3];
    const float* beta   = (const float*)d_in[4];
    const float* rmean  = (const float*)d_in[5];
    const float* rvar   = (const float*)d_in[6];
    float* out = (float*)d_out;

    // workspace layout (bytes)
    //   Wt      @ 0          : 9*512*256*2    = 2,359,296
    //   x_pad   @ 2359296    : 32*66*66*128*2 = 35,684,352
    //   h_pad   @ 38043648   : 32*66*66*128*2 = 35,684,352   (slot b*8+t = h after step t)
    //   c_state @ 73728000   : 128*16384*4    = 8,388,608    ([c][m]; written before read)
    //   total 82,116,608
    if (ws_size < 82116608u) return;

    char* ws = (char*)d_ws;
    __hip_bfloat16* Wt    = (__hip_bfloat16*)(ws);
    __hip_bfloat16* x_pad = (__hip_bfloat16*)(ws + 2359296);
    __hip_bfloat16* h_pad = (__hip_bfloat16*)(ws + 38043648);
    float* c_state        = (float*)(ws + 73728000);

    wt_kernel<<<4608, 256, 0, stream>>>(w_conv, Wt);
    xpose_kernel<<<2048, 256, 0, stream>>>(x, x_pad);
    border_kernel<<<64, 256, 0, stream>>>(x_pad, h_pad);

    conv_gemm<true><<<512, 256, 0, stream>>>(x_pad, h_pad, Wt, b_conv,
                                             gamma, beta, rmean, rvar, c_state, out, 0);
    for (int t = 1; t < 8; ++t)
        conv_gemm<false><<<512, 256, 0, stream>>>(x_pad, h_pad, Wt, b_conv,
                                                  gamma, beta, rmean, rvar, c_state, out, t);
}